// Round 1
// baseline (3548.265 us; speedup 1.0000x reference)
//
#include <hip/hip_runtime.h>
#include <math.h>

// FusionNeRF: two 5-layer MLPs (static 90->256x4->4, dynamic 99->256x4->5) over
// R*S = 2048*128 samples, sigmoid blend, then per-ray volume compositing.
//
// Round 1: correctness-first fp32 baseline.
//   Kernel 1 (nerf_mlp): 32 samples/block; encodings in LDS; register-blocked
//     fp32 GEMM (8 samples x 4 neurons per thread); in-place LDS ping-pong.
//   Kernel 2 (nerf_comp): thread-per-ray sequential compositing (exact ref math).

#define RAYS 2048
#define SAMP 128
#define MTOT (RAYS * SAMP)   // 262144 samples
#define HD   256             // hidden dim
#define MT   32              // samples per block
#define ENCD 99              // dynamic input dim (static input = first 90 dims)
#define ENCP 100             // padded LDS stride (400B rows, 16B aligned)

// flat output offsets (floats): rgb_map[2048,3], depth[2048], weights[2048,128],
// static_weights, dynamic_weights
#define OUT_RGB   0
#define OUT_DEPTH 6144
#define OUT_W     8192
#define OUT_SW    270336
#define OUT_DW    532480

__device__ __forceinline__ float sigm(float x) { return 1.0f / (1.0f + expf(-x)); }

// out[s][n] = act( in[s][0:K] @ W[K][256] + b[n] ), out stride = HD.
// in may alias out (internal barrier between reads and write-back).
// Thread t: sample group g = t>>6 (8 samples), neurons n0 = (t&63)*4.
// LDS A-reads are wave-uniform (broadcast, conflict-free); W reads coalesced float4.
template <bool RELU>
__device__ __forceinline__ void dense256(const float* in, int inS, int K,
                                         const float* __restrict__ W,
                                         const float* __restrict__ b,
                                         float* out, int tid)
{
    const int g   = tid >> 6;
    const int n0  = (tid & 63) << 2;
    const int sb0 = g << 3;

    float acc[8][4];
#pragma unroll
    for (int s = 0; s < 8; s++) { acc[s][0] = 0.f; acc[s][1] = 0.f; acc[s][2] = 0.f; acc[s][3] = 0.f; }

    int k = 0;
    for (; k + 4 <= K; k += 4) {
        const float4 w0 = *(const float4*)(W + (size_t)(k + 0) * HD + n0);
        const float4 w1 = *(const float4*)(W + (size_t)(k + 1) * HD + n0);
        const float4 w2 = *(const float4*)(W + (size_t)(k + 2) * HD + n0);
        const float4 w3 = *(const float4*)(W + (size_t)(k + 3) * HD + n0);
#pragma unroll
        for (int s = 0; s < 8; s++) {
            const float4 a = *(const float4*)(in + (sb0 + s) * inS + k);
            acc[s][0] += a.x * w0.x + a.y * w1.x + a.z * w2.x + a.w * w3.x;
            acc[s][1] += a.x * w0.y + a.y * w1.y + a.z * w2.y + a.w * w3.y;
            acc[s][2] += a.x * w0.z + a.y * w1.z + a.z * w2.z + a.w * w3.z;
            acc[s][3] += a.x * w0.w + a.y * w1.w + a.z * w2.w + a.w * w3.w;
        }
    }
    for (; k < K; k++) {  // remainder (K=90: 2, K=99: 3)
        const float4 w0 = *(const float4*)(W + (size_t)k * HD + n0);
#pragma unroll
        for (int s = 0; s < 8; s++) {
            const float a = in[(sb0 + s) * inS + k];
            acc[s][0] += a * w0.x; acc[s][1] += a * w0.y;
            acc[s][2] += a * w0.z; acc[s][3] += a * w0.w;
        }
    }

    __syncthreads();  // all reads of `in` done (in may alias out)

    const float4 bb = *(const float4*)(b + n0);
#pragma unroll
    for (int s = 0; s < 8; s++) {
        float4 o;
        o.x = acc[s][0] + bb.x; o.y = acc[s][1] + bb.y;
        o.z = acc[s][2] + bb.z; o.w = acc[s][3] + bb.w;
        if (RELU) {
            o.x = fmaxf(o.x, 0.f); o.y = fmaxf(o.y, 0.f);
            o.z = fmaxf(o.z, 0.f); o.w = fmaxf(o.w, 0.f);
        }
        *(float4*)(out + (sb0 + s) * HD + n0) = o;
    }
}

__global__ __launch_bounds__(256, 2)
void nerf_mlp(const float* __restrict__ points, const float* __restrict__ dirsv,
              const float* __restrict__ timev,
              const float* __restrict__ sW0, const float* __restrict__ sb0,
              const float* __restrict__ sW1, const float* __restrict__ sb1,
              const float* __restrict__ sW2, const float* __restrict__ sb2,
              const float* __restrict__ sW3, const float* __restrict__ sb3,
              const float* __restrict__ sW4, const float* __restrict__ sb4,
              const float* __restrict__ dW0, const float* __restrict__ db0,
              const float* __restrict__ dW1, const float* __restrict__ db1,
              const float* __restrict__ dW2, const float* __restrict__ db2,
              const float* __restrict__ dW3, const float* __restrict__ db3,
              const float* __restrict__ dW4, const float* __restrict__ db4,
              float* __restrict__ o_sigma, float* __restrict__ o_r,
              float* __restrict__ o_g, float* __restrict__ o_b,
              float* __restrict__ o_bw)
{
    __shared__ float enc[MT][ENCP];  // 12.8 KB: [p(3), sincos_p(60), d(3), sincos_d(24), t(1), sincos_t(8)]
    __shared__ float buf[MT][HD];    // 32 KB activation ping-pong (in-place)
    __shared__ float so[MT][4];
    __shared__ float dn[MT][5];

    const int tid = threadIdx.x;
    const int m0  = blockIdx.x * MT;

    // ---- positional encodings ----
    // torch order per band l: [sin(2^l * x) (C dims), cos(2^l * x) (C dims)]
    for (int idx = tid; idx < MT * ENCD; idx += 256) {
        const int s = idx / ENCD;
        const int d = idx - s * ENCD;
        const int m = m0 + s;
        float v;
        if (d < 3) {
            v = points[m * 3 + d];
        } else if (d < 63) {
            int q = d - 3;
            const int l = q / 6;
            const int r = q - l * 6;
            const int c = (r < 3) ? r : r - 3;
            const float x = points[m * 3 + c] * (float)(1 << l);
            v = (r < 3) ? sinf(x) : cosf(x);
        } else if (d < 90) {
            int q = d - 63;
            if (q < 3) {
                v = dirsv[m * 3 + q];
            } else {
                q -= 3;
                const int l = q / 6;
                const int r = q - l * 6;
                const int c = (r < 3) ? r : r - 3;
                const float x = dirsv[m * 3 + c] * (float)(1 << l);
                v = (r < 3) ? sinf(x) : cosf(x);
            }
        } else {
            int q = d - 90;
            const float t = timev[m];
            if (q == 0) {
                v = t;
            } else {
                q -= 1;
                const int l = q >> 1;
                const float x = t * (float)(1 << l);
                v = ((q & 1) == 0) ? sinf(x) : cosf(x);
            }
        }
        enc[s][d] = v;
    }
    __syncthreads();

    // ---- static MLP: enc[0:90] -> 256 -> 256 -> 256 -> 256 -> 4 ----
    dense256<true>(&enc[0][0], ENCP, 90, sW0, sb0, &buf[0][0], tid); __syncthreads();
    dense256<true>(&buf[0][0], HD,   HD, sW1, sb1, &buf[0][0], tid); __syncthreads();
    dense256<true>(&buf[0][0], HD,   HD, sW2, sb2, &buf[0][0], tid); __syncthreads();
    dense256<true>(&buf[0][0], HD,   HD, sW3, sb3, &buf[0][0], tid); __syncthreads();

    // static head: 256 -> 4 (linear). 128 threads: (s, n) = (t>>2, t&3)
    if (tid < MT * 4) {
        const int s = tid >> 2, n = tid & 3;
        float acc = sb4[n];
        const float* row = &buf[s][0];
        for (int k = 0; k < HD; k += 4) {
            const float4 a = *(const float4*)(row + k);
            acc += a.x * sW4[(k + 0) * 4 + n] + a.y * sW4[(k + 1) * 4 + n]
                 + a.z * sW4[(k + 2) * 4 + n] + a.w * sW4[(k + 3) * 4 + n];
        }
        so[s][n] = acc;
    }
    // NOTE: no explicit sync needed before dynamic L0 write-back: dense256's
    // internal barrier (before its buf write) orders the head's buf reads.

    // ---- dynamic MLP: enc[0:99] -> 256 -> 256 -> 256 -> 256 -> 5 ----
    dense256<true>(&enc[0][0], ENCP, 99, dW0, db0, &buf[0][0], tid); __syncthreads();
    dense256<true>(&buf[0][0], HD,   HD, dW1, db1, &buf[0][0], tid); __syncthreads();
    dense256<true>(&buf[0][0], HD,   HD, dW2, db2, &buf[0][0], tid); __syncthreads();
    dense256<true>(&buf[0][0], HD,   HD, dW3, db3, &buf[0][0], tid); __syncthreads();

    // dynamic head: 256 -> 5 (linear). 160 threads: s = t/5, n = t%5
    if (tid < MT * 5) {
        const int s = tid / 5, n = tid - 5 * s;
        float acc = db4[n];
        const float* row = &buf[s][0];
        for (int k = 0; k < HD; k += 4) {
            const float4 a = *(const float4*)(row + k);
            acc += a.x * dW4[(k + 0) * 5 + n] + a.y * dW4[(k + 1) * 5 + n]
                 + a.z * dW4[(k + 2) * 5 + n] + a.w * dW4[(k + 3) * 5 + n];
        }
        dn[s][n] = acc;
    }
    __syncthreads();

    // ---- blend + per-sample output ----
    if (tid < MT) {
        const int s = tid, m = m0 + s;
        const float bw = sigm(dn[s][4]);
        const float sigma = (1.f - bw) * so[s][0] + bw * dn[s][0];
        const float r  = (1.f - bw) * sigm(so[s][1]) + bw * sigm(dn[s][1]);
        const float gg = (1.f - bw) * sigm(so[s][2]) + bw * sigm(dn[s][2]);
        const float bb = (1.f - bw) * sigm(so[s][3]) + bw * sigm(dn[s][3]);
        o_sigma[m] = sigma; o_r[m] = r; o_g[m] = gg; o_b[m] = bb; o_bw[m] = bw;
    }
}

__global__ __launch_bounds__(256)
void nerf_comp(const float* __restrict__ zv,
               const float* __restrict__ o_sigma, const float* __restrict__ o_r,
               const float* __restrict__ o_g, const float* __restrict__ o_b,
               const float* __restrict__ o_bw, float* __restrict__ out)
{
    const int r = blockIdx.x * blockDim.x + threadIdx.x;
    if (r >= RAYS) return;
    const int base = r * SAMP;
    float trans = 1.f, cr = 0.f, cg = 0.f, cb = 0.f, cd = 0.f;
    float z = zv[base];
    for (int s = 0; s < SAMP; s++) {
        const float znext = (s < SAMP - 1) ? zv[base + s + 1] : 0.f;
        const float delta = (s < SAMP - 1) ? (znext - z) : 1e10f;
        const float sigma = o_sigma[base + s];
        const float alpha = 1.f - expf(-sigma * delta);
        const float w = alpha * trans;
        const float bw = o_bw[base + s];
        out[OUT_W  + base + s] = w;
        out[OUT_SW + base + s] = (1.f - bw) * w;
        out[OUT_DW + base + s] = bw * w;
        cr += w * o_r[base + s];
        cg += w * o_g[base + s];
        cb += w * o_b[base + s];
        cd += w * z;
        trans *= (1.f - alpha + 1e-10f);  // trans[s] = prod_{j<s}(1-alpha_j+1e-10)
        z = znext;
    }
    out[OUT_RGB + r * 3 + 0] = cr;
    out[OUT_RGB + r * 3 + 1] = cg;
    out[OUT_RGB + r * 3 + 2] = cb;
    out[OUT_DEPTH + r] = cd;
}

extern "C" void kernel_launch(void* const* d_in, const int* in_sizes, int n_in,
                              void* d_out, int out_size, void* d_ws, size_t ws_size,
                              hipStream_t stream)
{
    const float* points = (const float*)d_in[0];
    const float* dirsv  = (const float*)d_in[1];
    const float* zvals  = (const float*)d_in[2];
    const float* timev  = (const float*)d_in[3];

    const float *sW[5], *sb[5], *dW[5], *db[5];
    if (in_sizes[6] == 99 * 256) {
        // setup_inputs() dict order: interleaved per layer (sW_i, sb_i, dW_i, db_i)
        for (int i = 0; i < 5; i++) {
            sW[i] = (const float*)d_in[4 + 4 * i + 0];
            sb[i] = (const float*)d_in[4 + 4 * i + 1];
            dW[i] = (const float*)d_in[4 + 4 * i + 2];
            db[i] = (const float*)d_in[4 + 4 * i + 3];
        }
    } else {
        // fallback: all static pairs then all dynamic pairs (reference arg order)
        for (int i = 0; i < 5; i++) {
            sW[i] = (const float*)d_in[4 + 2 * i + 0];
            sb[i] = (const float*)d_in[4 + 2 * i + 1];
            dW[i] = (const float*)d_in[14 + 2 * i + 0];
            db[i] = (const float*)d_in[14 + 2 * i + 1];
        }
    }

    // workspace: 5 per-sample arrays (sigma, r, g, b, bw) = 5.24 MB
    float* ws = (float*)d_ws;
    float* o_sigma = ws;
    float* o_r  = ws + (size_t)MTOT * 1;
    float* o_g  = ws + (size_t)MTOT * 2;
    float* o_b  = ws + (size_t)MTOT * 3;
    float* o_bw = ws + (size_t)MTOT * 4;

    nerf_mlp<<<MTOT / MT, 256, 0, stream>>>(points, dirsv, timev,
        sW[0], sb[0], sW[1], sb[1], sW[2], sb[2], sW[3], sb[3], sW[4], sb[4],
        dW[0], db[0], dW[1], db[1], dW[2], db[2], dW[3], db[3], dW[4], db[4],
        o_sigma, o_r, o_g, o_b, o_bw);

    nerf_comp<<<(RAYS + 255) / 256, 256, 0, stream>>>(zvals, o_sigma, o_r, o_g, o_b, o_bw,
                                                      (float*)d_out);
}

// Round 2
// 679.988 us; speedup vs baseline: 5.2181x; 5.2181x over previous
//
#include <hip/hip_runtime.h>
#include <math.h>

// FusionNeRF round 2: MFMA bf16 MLP.
//   prep_weights: fp32 W[K][N] -> bf16 Wt[Npad][Kpad] (k-contiguous, zero-padded)
//   nerf_mlp: 64 samples/block, 4 waves x (64x64 tile as 4x4 mfma_f32_16x16x32_bf16),
//             single in-place LDS activation buffer, enc buffer shared by both MLPs.
//   nerf_comp: wave-per-ray, multiplicative shuffle scan for transmittance.

#define RAYS 2048
#define SAMP 128
#define MTOT (RAYS * SAMP)
#define HD   256
#define BM   64              // samples per block
#define ES   136             // enc LDS stride (bf16), Kpad=128 (+8 pad)
#define HS   264             // hidden LDS stride (bf16), 256 (+8 pad)

// output float offsets
#define OUT_RGB   0
#define OUT_DEPTH 6144
#define OUT_W     8192
#define OUT_SW    270336
#define OUT_DW    532480

// bf16 weight workspace offsets (elements)
#define SW0 0
#define SW1 32768
#define SW2 98304
#define SW3 163840
#define SW4 229376
#define DW0 233472
#define DW1 266240
#define DW2 331776
#define DW3 397312
#define DW4 462848
#define WTOT 466944

typedef __attribute__((ext_vector_type(8))) short short8;
typedef __attribute__((ext_vector_type(4))) float f32x4;

__device__ __forceinline__ float sigm(float x) { return 1.0f / (1.0f + expf(-x)); }

__device__ __forceinline__ short f2bf(float f) {   // RNE fp32 -> bf16
    union { float f; unsigned u; } v; v.f = f;
    unsigned r = v.u + 0x7fffu + ((v.u >> 16) & 1u);
    return (short)(r >> 16);
}

// ---------------- weight prep: W[K][N] fp32 -> Wt[Npad][Kpad] bf16 ----------------
__device__ __forceinline__ void conv1(const float* __restrict__ src, short* __restrict__ dst,
                                      int local, int K, int N, int Kpad) {
    const int n = local / Kpad, k = local - n * Kpad;
    const float v = (k < K && n < N) ? src[k * N + n] : 0.0f;
    dst[local] = f2bf(v);
}

__global__ __launch_bounds__(256)
void prep_weights(const float* sW0, const float* sW1, const float* sW2,
                  const float* sW3, const float* sW4,
                  const float* dW0, const float* dW1, const float* dW2,
                  const float* dW3, const float* dW4, short* __restrict__ dst)
{
    const int idx = blockIdx.x * 256 + threadIdx.x;
    if (idx >= WTOT) return;
    if      (idx < SW1) conv1(sW0, dst + SW0, idx - SW0,  90, 256, 128);
    else if (idx < SW2) conv1(sW1, dst + SW1, idx - SW1, 256, 256, 256);
    else if (idx < SW3) conv1(sW2, dst + SW2, idx - SW2, 256, 256, 256);
    else if (idx < SW4) conv1(sW3, dst + SW3, idx - SW3, 256, 256, 256);
    else if (idx < DW0) conv1(sW4, dst + SW4, idx - SW4, 256,   4, 256);
    else if (idx < DW1) conv1(dW0, dst + DW0, idx - DW0,  99, 256, 128);
    else if (idx < DW2) conv1(dW1, dst + DW1, idx - DW1, 256, 256, 256);
    else if (idx < DW3) conv1(dW2, dst + DW2, idx - DW2, 256, 256, 256);
    else if (idx < DW4) conv1(dW3, dst + DW3, idx - DW3, 256, 256, 256);
    else                conv1(dW4, dst + DW4, idx - DW4, 256,   5, 256);
}

// ---------------- MFMA dense layer: A[64][K] (LDS bf16) @ Wt[256][K]^T -> O[64][256] ----------------
// Wave w covers output cols [64w, 64w+64). A may alias O (internal barrier).
template <int KSTEPS, bool RELU>
__device__ __forceinline__ void layer256(const short* A, int As,
                                         const short* __restrict__ Wt,
                                         const float* __restrict__ bias,
                                         short* O, int Os, int tid)
{
    const int w = tid >> 6, lane = tid & 63, q = lane >> 4, col = lane & 15;
    const int K = KSTEPS * 32;

    f32x4 acc[4][4];
#pragma unroll
    for (int mt = 0; mt < 4; mt++)
#pragma unroll
        for (int nt = 0; nt < 4; nt++) acc[mt][nt] = (f32x4)0.0f;

    const short* wbase = Wt + (size_t)(w * 64) * K + q * 8;
#pragma unroll
    for (int kk = 0; kk < KSTEPS; kk++) {
        short8 a[4], b[4];
#pragma unroll
        for (int mt = 0; mt < 4; mt++)
            a[mt] = *(const short8*)(A + (mt * 16 + col) * As + kk * 32 + q * 8);
#pragma unroll
        for (int nt = 0; nt < 4; nt++)
            b[nt] = *(const short8*)(wbase + (size_t)(nt * 16 + col) * K + kk * 32);
#pragma unroll
        for (int mt = 0; mt < 4; mt++)
#pragma unroll
            for (int nt = 0; nt < 4; nt++)
                acc[mt][nt] = __builtin_amdgcn_mfma_f32_16x16x32_bf16(a[mt], b[nt], acc[mt][nt], 0, 0, 0);
    }

    __syncthreads();  // all waves done reading A (A may alias O)

    float bv[4];
#pragma unroll
    for (int nt = 0; nt < 4; nt++) bv[nt] = bias[w * 64 + nt * 16 + col];
#pragma unroll
    for (int mt = 0; mt < 4; mt++)
#pragma unroll
        for (int nt = 0; nt < 4; nt++)
#pragma unroll
            for (int i = 0; i < 4; i++) {
                float v = acc[mt][nt][i] + bv[nt];
                if (RELU) v = fmaxf(v, 0.0f);
                O[(mt * 16 + q * 4 + i) * Os + w * 64 + nt * 16 + col] = f2bf(v);
            }
    __syncthreads();  // O visible to next layer
}

// head: A[64][256] @ Wt[16][256]^T -> Out[64][NV] (+bias), wave w does rows 16w..16w+15
template <int NV>
__device__ __forceinline__ void head256(const short* A, int As,
                                        const short* __restrict__ Wt,
                                        const float* __restrict__ bias,
                                        float* Out, int tid)
{
    const int w = tid >> 6, lane = tid & 63, q = lane >> 4, col = lane & 15;
    f32x4 acc = (f32x4)0.0f;
#pragma unroll
    for (int kk = 0; kk < 8; kk++) {
        short8 a = *(const short8*)(A + (w * 16 + col) * As + kk * 32 + q * 8);
        short8 b = *(const short8*)(Wt + col * 256 + kk * 32 + q * 8);
        acc = __builtin_amdgcn_mfma_f32_16x16x32_bf16(a, b, acc, 0, 0, 0);
    }
    if (col < NV) {
#pragma unroll
        for (int i = 0; i < 4; i++)
            Out[(w * 16 + q * 4 + i) * NV + col] = acc[i] + bias[col];
    }
}

__global__ __launch_bounds__(256, 3)
void nerf_mlp(const float* __restrict__ points, const float* __restrict__ dirsv,
              const float* __restrict__ timev, const short* __restrict__ wt,
              const float* __restrict__ sb0, const float* __restrict__ sb1,
              const float* __restrict__ sb2, const float* __restrict__ sb3,
              const float* __restrict__ sb4,
              const float* __restrict__ db0, const float* __restrict__ db1,
              const float* __restrict__ db2, const float* __restrict__ db3,
              const float* __restrict__ db4,
              float* __restrict__ o_sigma, float* __restrict__ o_r,
              float* __restrict__ o_g, float* __restrict__ o_b,
              float* __restrict__ o_bw)
{
    __shared__ short E[BM][ES];   // 17.0 KB: encoding, Kpad=128 (zeros for d>=99)
    __shared__ short Hb[BM][HS];  // 33.0 KB: activations, updated in-place
    __shared__ float so[BM][4];
    __shared__ float dn[BM][5];

    const int tid = threadIdx.x;
    const int m0  = blockIdx.x * BM;

    // ---- positional encoding -> E (bf16), torch order [x, sin(f0 x), cos(f0 x), ...] ----
    for (int idx = tid; idx < BM * 128; idx += 256) {
        const int s = idx >> 7;
        const int d = idx & 127;
        const int m = m0 + s;
        float v = 0.0f;
        if (d < 3) {
            v = points[m * 3 + d];
        } else if (d < 63) {
            int qq = d - 3;
            const int l = qq / 6, r = qq - l * 6;
            const int c = (r < 3) ? r : r - 3;
            const float x = points[m * 3 + c] * (float)(1 << l);
            v = (r < 3) ? sinf(x) : cosf(x);
        } else if (d < 90) {
            int qq = d - 63;
            if (qq < 3) v = dirsv[m * 3 + qq];
            else {
                qq -= 3;
                const int l = qq / 6, r = qq - l * 6;
                const int c = (r < 3) ? r : r - 3;
                const float x = dirsv[m * 3 + c] * (float)(1 << l);
                v = (r < 3) ? sinf(x) : cosf(x);
            }
        } else if (d < 99) {
            int qq = d - 90;
            const float t = timev[m];
            if (qq == 0) v = t;
            else {
                qq -= 1;
                const float x = t * (float)(1 << (qq >> 1));
                v = ((qq & 1) == 0) ? sinf(x) : cosf(x);
            }
        }
        E[s][d] = f2bf(v);
    }
    __syncthreads();

    // ---- static MLP ----
    layer256<4, true>(&E[0][0],  ES, wt + SW0, sb0, &Hb[0][0], HS, tid);
    layer256<8, true>(&Hb[0][0], HS, wt + SW1, sb1, &Hb[0][0], HS, tid);
    layer256<8, true>(&Hb[0][0], HS, wt + SW2, sb2, &Hb[0][0], HS, tid);
    layer256<8, true>(&Hb[0][0], HS, wt + SW3, sb3, &Hb[0][0], HS, tid);
    head256<4>(&Hb[0][0], HS, wt + SW4, sb4, &so[0][0], tid);
    // (ordering: dynamic layer0's internal barrier sits between these head reads
    //  of Hb and its own Hb overwrite)

    // ---- dynamic MLP ----
    layer256<4, true>(&E[0][0],  ES, wt + DW0, db0, &Hb[0][0], HS, tid);
    layer256<8, true>(&Hb[0][0], HS, wt + DW1, db1, &Hb[0][0], HS, tid);
    layer256<8, true>(&Hb[0][0], HS, wt + DW2, db2, &Hb[0][0], HS, tid);
    layer256<8, true>(&Hb[0][0], HS, wt + DW3, db3, &Hb[0][0], HS, tid);
    head256<5>(&Hb[0][0], HS, wt + DW4, db4, &dn[0][0], tid);
    __syncthreads();

    // ---- blend ----
    if (tid < BM) {
        const int s = tid, m = m0 + s;
        const float bw = sigm(dn[s][4]);
        const float sigma = (1.f - bw) * so[s][0] + bw * dn[s][0];
        const float r  = (1.f - bw) * sigm(so[s][1]) + bw * sigm(dn[s][1]);
        const float gg = (1.f - bw) * sigm(so[s][2]) + bw * sigm(dn[s][2]);
        const float bb = (1.f - bw) * sigm(so[s][3]) + bw * sigm(dn[s][3]);
        o_sigma[m] = sigma; o_r[m] = r; o_g[m] = gg; o_b[m] = bb; o_bw[m] = bw;
    }
}

// ---------------- compositing: one wave per ray, shuffle scan ----------------
__global__ __launch_bounds__(256)
void nerf_comp(const float* __restrict__ zv,
               const float* __restrict__ o_sigma, const float* __restrict__ o_r,
               const float* __restrict__ o_g, const float* __restrict__ o_b,
               const float* __restrict__ o_bw, float* __restrict__ out)
{
    const int ray  = blockIdx.x * 4 + (threadIdx.x >> 6);
    const int lane = threadIdx.x & 63;
    const int base = ray * SAMP;
    const int s0 = 2 * lane, s1 = s0 + 1;

    const float z0 = zv[base + s0];
    const float z1 = zv[base + s1];
    const float z2 = (lane < 63) ? zv[base + s1 + 1] : 0.0f;
    const float d0 = z1 - z0;
    const float d1 = (lane < 63) ? (z2 - z1) : 1e10f;

    const float sg0 = o_sigma[base + s0], sg1 = o_sigma[base + s1];
    const float a0 = 1.0f - expf(-sg0 * d0);
    const float a1 = 1.0f - expf(-sg1 * d1);
    const float f0 = 1.0f - a0 + 1e-10f;
    const float f1 = 1.0f - a1 + 1e-10f;

    // inclusive multiplicative scan of p = f0*f1 across lanes
    float incl = f0 * f1;
#pragma unroll
    for (int dlt = 1; dlt < 64; dlt <<= 1) {
        const float t = __shfl_up(incl, dlt);
        if (lane >= dlt) incl *= t;
    }
    float ex = __shfl_up(incl, 1);
    if (lane == 0) ex = 1.0f;

    const float t0 = ex;          // trans for s0
    const float t1 = ex * f0;     // trans for s1
    const float w0 = a0 * t0, w1 = a1 * t1;

    const float bw0 = o_bw[base + s0], bw1 = o_bw[base + s1];
    out[OUT_W  + base + s0] = w0;             out[OUT_W  + base + s1] = w1;
    out[OUT_SW + base + s0] = (1.f - bw0) * w0; out[OUT_SW + base + s1] = (1.f - bw1) * w1;
    out[OUT_DW + base + s0] = bw0 * w0;       out[OUT_DW + base + s1] = bw1 * w1;

    float pr = w0 * o_r[base + s0] + w1 * o_r[base + s1];
    float pg = w0 * o_g[base + s0] + w1 * o_g[base + s1];
    float pb = w0 * o_b[base + s0] + w1 * o_b[base + s1];
    float pd = w0 * z0 + w1 * z1;
#pragma unroll
    for (int dlt = 32; dlt >= 1; dlt >>= 1) {
        pr += __shfl_down(pr, dlt);
        pg += __shfl_down(pg, dlt);
        pb += __shfl_down(pb, dlt);
        pd += __shfl_down(pd, dlt);
    }
    if (lane == 0) {
        out[OUT_RGB + ray * 3 + 0] = pr;
        out[OUT_RGB + ray * 3 + 1] = pg;
        out[OUT_RGB + ray * 3 + 2] = pb;
        out[OUT_DEPTH + ray] = pd;
    }
}

extern "C" void kernel_launch(void* const* d_in, const int* in_sizes, int n_in,
                              void* d_out, int out_size, void* d_ws, size_t ws_size,
                              hipStream_t stream)
{
    const float* points = (const float*)d_in[0];
    const float* dirsv  = (const float*)d_in[1];
    const float* zvals  = (const float*)d_in[2];
    const float* timev  = (const float*)d_in[3];

    const float *sW[5], *sb[5], *dW[5], *db[5];
    if (in_sizes[6] == 99 * 256) {
        for (int i = 0; i < 5; i++) {   // interleaved (sW_i, sb_i, dW_i, db_i)
            sW[i] = (const float*)d_in[4 + 4 * i + 0];
            sb[i] = (const float*)d_in[4 + 4 * i + 1];
            dW[i] = (const float*)d_in[4 + 4 * i + 2];
            db[i] = (const float*)d_in[4 + 4 * i + 3];
        }
    } else {
        for (int i = 0; i < 5; i++) {   // all static then all dynamic
            sW[i] = (const float*)d_in[4 + 2 * i + 0];
            sb[i] = (const float*)d_in[4 + 2 * i + 1];
            dW[i] = (const float*)d_in[14 + 2 * i + 0];
            db[i] = (const float*)d_in[14 + 2 * i + 1];
        }
    }

    // ws layout: bf16 weights (933888 B) then 5 fp32 per-sample arrays (1 MB each)
    short* wt = (short*)d_ws;
    float* ws = (float*)((char*)d_ws + (size_t)WTOT * 2);
    float* o_sigma = ws;
    float* o_r  = ws + (size_t)MTOT * 1;
    float* o_g  = ws + (size_t)MTOT * 2;
    float* o_b  = ws + (size_t)MTOT * 3;
    float* o_bw = ws + (size_t)MTOT * 4;

    prep_weights<<<(WTOT + 255) / 256, 256, 0, stream>>>(
        sW[0], sW[1], sW[2], sW[3], sW[4], dW[0], dW[1], dW[2], dW[3], dW[4], wt);

    nerf_mlp<<<MTOT / BM, 256, 0, stream>>>(points, dirsv, timev, wt,
        sb[0], sb[1], sb[2], sb[3], sb[4], db[0], db[1], db[2], db[3], db[4],
        o_sigma, o_r, o_g, o_b, o_bw);

    nerf_comp<<<RAYS / 4, 256, 0, stream>>>(zvals, o_sigma, o_r, o_g, o_b, o_bw,
                                            (float*)d_out);
}